// Round 14
// baseline (506.615 us; speedup 1.0000x reference)
//
#include <hip/hip_runtime.h>
#include <hip/hip_fp16.h>

#define N_NODES 100000
#define N_EDGES 1600000
#define EMAX4   1900000                 // mult-of-4-padded edge capacity (E + 3*N)
#define N_GRAPHS 2048
#define HID 64
#define IN_F 14
#define N_CLS 2
#define EPS 1e-5f

#define BSHIFT 9
#define NBUCK 196                       // ceil(100000 / 512)
#define ABLOCKS 256
#define CHUNK (N_EDGES / ABLOCKS)       // 6250, exact

#define NBLK2 128                       // node-sort blocks
#define NCHUNK2 ((N_NODES + NBLK2 - 1) / NBLK2)  // 782

typedef _Float16 half_t;
typedef _Float16 half8 __attribute__((ext_vector_type(8)));
typedef float f32x4 __attribute__((ext_vector_type(4)));
typedef unsigned int u32;
typedef u32 u32x4 __attribute__((ext_vector_type(4)));
typedef u32 u32x2 __attribute__((ext_vector_type(2)));

__device__ __forceinline__ __half2 u32_as_half2(u32 u) {
    union { u32 u; __half2 h; } c;
    c.u = u;
    return c.h;
}

// ============ CSR build, atomic-free (global) two-level counting sort ========

__global__ __launch_bounds__(256) void histA_kernel(const int* __restrict__ col,
                                                    int* __restrict__ histG) {
    __shared__ int hl[NBUCK];
    for (int i = threadIdx.x; i < NBUCK; i += 256) hl[i] = 0;
    __syncthreads();
    int e0 = blockIdx.x * CHUNK;
    for (int e = e0 + threadIdx.x; e < e0 + CHUNK; e += 256)
        atomicAdd(&hl[col[e] >> BSHIFT], 1);
    __syncthreads();
    for (int i = threadIdx.x; i < NBUCK; i += 256)
        histG[i * ABLOCKS + blockIdx.x] = hl[i];
}

__global__ __launch_bounds__(256) void scanS1_kernel(const int* __restrict__ histG,
                                                     int* __restrict__ bsumA) {
    __shared__ int ls[256];
    ls[threadIdx.x] = histG[blockIdx.x * 256 + threadIdx.x];
    __syncthreads();
    for (int off = 128; off > 0; off >>= 1) {
        if (threadIdx.x < off) ls[threadIdx.x] += ls[threadIdx.x + off];
        __syncthreads();
    }
    if (threadIdx.x == 0) bsumA[blockIdx.x] = ls[0];
}

__global__ __launch_bounds__(512) void topscan_kernel(int* __restrict__ bsum, int nb) {
    __shared__ int ls[512];
    int t = threadIdx.x;
    int v = (t < nb) ? bsum[t] : 0;
    ls[t] = v;
    __syncthreads();
    for (int off = 1; off < 512; off <<= 1) {
        int x = ls[t];
        if (t >= off) x += ls[t - off];
        __syncthreads();
        ls[t] = x;
        __syncthreads();
    }
    if (t < nb) bsum[t] = ls[t] - v;  // exclusive
}

__global__ __launch_bounds__(256) void scanS3_kernel(int* __restrict__ histG,
                                                     const int* __restrict__ bsumA,
                                                     int* __restrict__ ptr) {
    __shared__ int ls[256];
    int idx = blockIdx.x * 256 + threadIdx.x;
    int v = histG[idx];
    ls[threadIdx.x] = v;
    __syncthreads();
    for (int off = 1; off < 256; off <<= 1) {
        int x = ls[threadIdx.x];
        if (threadIdx.x >= off) x += ls[threadIdx.x - off];
        __syncthreads();
        ls[threadIdx.x] = x;
        __syncthreads();
    }
    histG[idx] = ls[threadIdx.x] - v + bsumA[blockIdx.x];
    if (blockIdx.x == 0 && threadIdx.x == 0) ptr[N_NODES] = N_EDGES;
}

__global__ __launch_bounds__(256) void scatterA_kernel(const int* __restrict__ row,
                                                       const int* __restrict__ col,
                                                       const float* __restrict__ w,
                                                       const int* __restrict__ histG,
                                                       int2* __restrict__ EA) {
    __shared__ int cur[NBUCK];
    for (int i = threadIdx.x; i < NBUCK; i += 256)
        cur[i] = histG[i * ABLOCKS + blockIdx.x];
    __syncthreads();
    int e0 = blockIdx.x * CHUNK;
    for (int e = e0 + threadIdx.x; e < e0 + CHUNK; e += 256) {
        int c = col[e];
        int r = row[e];
        int fx = (int)__float2uint_rn(w[e] * 8192.0f);   // 15-bit fixed, exact for w=1
        int pos = atomicAdd(&cur[c >> BSHIFT], 1);        // LDS atomic
        EA[pos] = make_int2(r, (fx << 17) | c);
    }
}

// bucketA: per-bucket dense hist+scan -> ptr (unpadded CSR base), dinv
__global__ __launch_bounds__(256) void bucketA_kernel(const int2* __restrict__ EA,
                                                      const int* __restrict__ bsumA,
                                                      int* __restrict__ ptr,
                                                      float* __restrict__ dinv) {
    __shared__ int hist[512], wsum[512];
    int b = blockIdx.x;
    int beg = bsumA[b];
    int end = (b == NBUCK - 1) ? N_EDGES : bsumA[b + 1];
    int i0 = threadIdx.x, i1 = threadIdx.x + 256;
    hist[i0] = 0; hist[i1] = 0;
    wsum[i0] = 0; wsum[i1] = 0;
    __syncthreads();
    for (int e = beg + threadIdx.x; e < end; e += 256) {
        int2 ed = EA[e];
        int c9 = ed.y & 511;
        atomicAdd(&hist[c9], 1);
        atomicAdd(&wsum[c9], (int)((unsigned int)ed.y >> 17));
    }
    __syncthreads();
    int cnt0 = hist[i0], cnt1 = hist[i1];
    for (int off = 1; off < 512; off <<= 1) {
        int v0 = hist[i0], v1 = hist[i1];
        int a0 = (i0 >= off) ? hist[i0 - off] : 0;
        int a1 = (i1 >= off) ? hist[i1 - off] : 0;
        __syncthreads();
        hist[i0] = v0 + a0;
        hist[i1] = v1 + a1;
        __syncthreads();
    }
    int excl0 = hist[i0] - cnt0, excl1 = hist[i1] - cnt1;
    int col0 = (b << BSHIFT) + i0, col1 = (b << BSHIFT) + i1;
    if (col0 < N_NODES) {
        ptr[col0] = beg + excl0;
        dinv[col0] = rsqrtf(1.0f + (float)wsum[i0] * (1.0f / 8192.0f));
    }
    if (col1 < N_NODES) {
        ptr[col1] = beg + excl1;
        dinv[col1] = rsqrtf(1.0f + (float)wsum[i1] * (1.0f / 8192.0f));
    }
}

// ============ node degree sort (mult-of-4-padded edge layout) ================

__global__ __launch_bounds__(256) void histD_kernel(const int* __restrict__ ptr,
                                                    int* __restrict__ histD) {
    __shared__ int hl[2048];
    for (int i = threadIdx.x; i < 2048; i += 256) hl[i] = 0;
    __syncthreads();
    int n0 = blockIdx.x * NCHUNK2;
    int n1 = n0 + NCHUNK2; if (n1 > N_NODES) n1 = N_NODES;
    for (int n = n0 + threadIdx.x; n < n1; n += 256) {
        int d = ptr[n + 1] - ptr[n];
        if (d > 255) d = 255;
        atomicAdd(&hl[((threadIdx.x & 7) << 8) + d], 1);
    }
    __syncthreads();
    int s = 0;
#pragma unroll
    for (int c = 0; c < 8; c++) s += hl[(c << 8) + threadIdx.x];
    histD[threadIdx.x * NBLK2 + blockIdx.x] = s;
}

__global__ __launch_bounds__(128) void scanD1_kernel(const int* __restrict__ histD,
                                                     int* __restrict__ rowTot) {
    __shared__ int ls[128];
    ls[threadIdx.x] = histD[blockIdx.x * NBLK2 + threadIdx.x];
    __syncthreads();
    for (int off = 64; off > 0; off >>= 1) {
        if (threadIdx.x < off) ls[threadIdx.x] += ls[threadIdx.x + off];
        __syncthreads();
    }
    if (threadIdx.x == 0) rowTot[blockIdx.x] = ls[0];
}

__global__ __launch_bounds__(256) void topscanD_kernel(const int* __restrict__ rowTot,
                                                       int* __restrict__ nodeExcl,
                                                       int* __restrict__ edgeExcl,
                                                       int* __restrict__ ptrS) {
    __shared__ int a[256], b[256];
    int t = threadIdx.x;
    int cnt = rowTot[t];
    int dpad = (t + 3) & ~3;
    int ec = cnt * dpad;
    a[t] = cnt; b[t] = ec;
    __syncthreads();
    for (int off = 1; off < 256; off <<= 1) {
        int va = a[t], vb = b[t];
        if (t >= off) { va += a[t - off]; vb += b[t - off]; }
        __syncthreads();
        a[t] = va; b[t] = vb;
        __syncthreads();
    }
    nodeExcl[t] = a[t] - cnt;
    edgeExcl[t] = b[t] - ec;
    if (t == 255) ptrS[N_NODES] = b[255];   // total padded edges
}

__global__ __launch_bounds__(128) void scanD3_kernel(int* __restrict__ histD,
                                                     const int* __restrict__ nodeExcl) {
    __shared__ int ls[128];
    int idx = blockIdx.x * NBLK2 + threadIdx.x;
    int v = histD[idx];
    ls[threadIdx.x] = v;
    __syncthreads();
    for (int off = 1; off < 128; off <<= 1) {
        int x = ls[threadIdx.x];
        if (threadIdx.x >= off) x += ls[threadIdx.x - off];
        __syncthreads();
        ls[threadIdx.x] = x;
        __syncthreads();
    }
    histD[idx] = ls[threadIdx.x] - v + nodeExcl[blockIdx.x];
}

__global__ __launch_bounds__(256) void scatterD_kernel(const int* __restrict__ ptr,
                                                       const int* __restrict__ histD,
                                                       const int* __restrict__ nodeExcl,
                                                       const int* __restrict__ edgeExcl,
                                                       int* __restrict__ perm,
                                                       int* __restrict__ ptrS,
                                                       int* __restrict__ newbase) {
    __shared__ int cur[256];
    cur[threadIdx.x] = histD[threadIdx.x * NBLK2 + blockIdx.x];
    __syncthreads();
    int n0 = blockIdx.x * NCHUNK2;
    int n1 = n0 + NCHUNK2; if (n1 > N_NODES) n1 = N_NODES;
    for (int n = n0 + threadIdx.x; n < n1; n += 256) {
        int d = ptr[n + 1] - ptr[n];
        if (d > 255) d = 255;
        int dpad = (d + 3) & ~3;
        int pos = atomicAdd(&cur[d], 1);                  // LDS atomic
        int ebase = edgeExcl[d] + (pos - nodeExcl[d]) * dpad;
        perm[pos] = n;
        ptrS[pos] = ebase;
        newbase[n] = ebase;
    }
}

// bucketB: scatter EA directly to final split arrays (srcoff u32 = src*128B,
// norm fp16) at mult-of-4-padded degree-sorted positions. Padding pre-zeroed.
__global__ __launch_bounds__(256) void bucketB_kernel(const int2* __restrict__ EA,
                                                      const int* __restrict__ bsumA,
                                                      const int* __restrict__ newbase,
                                                      const float* __restrict__ dinv,
                                                      unsigned int* __restrict__ srcoff,
                                                      half_t* __restrict__ normh) {
    __shared__ int cur[512];
    int b = blockIdx.x;
    int beg = bsumA[b];
    int end = (b == NBUCK - 1) ? N_EDGES : bsumA[b + 1];
    int i0 = threadIdx.x, i1 = threadIdx.x + 256;
    int col0 = (b << BSHIFT) + i0, col1 = (b << BSHIFT) + i1;
    cur[i0] = (col0 < N_NODES) ? newbase[col0] : 0;
    cur[i1] = (col1 < N_NODES) ? newbase[col1] : 0;
    __syncthreads();
    for (int e = beg + threadIdx.x; e < end; e += 256) {
        int2 ed = EA[e];
        int c = ed.y & 0x1ffff;
        float w = (float)((unsigned int)ed.y >> 17) * (1.0f / 8192.0f);
        float nrm = dinv[ed.x] * w * dinv[c];
        int pos = atomicAdd(&cur[c & 511], 1);            // LDS atomic
        srcoff[pos] = (unsigned int)ed.x << 7;            // byte offset into xw rows
        normh[pos] = (half_t)nrm;
    }
}

// ---------------- layer-1 GEMM (K=14, VALU), interleaved store -------------

template <int K>
__global__ __launch_bounds__(256) void gemm_kernel(const float* __restrict__ h,
                                                   const float* __restrict__ W,
                                                   half_t* __restrict__ xw, int n_nodes) {
    int f = threadIdx.x & 63;
    float wcol[K];
#pragma unroll
    for (int k = 0; k < K; k++) wcol[k] = W[k * HID + f];
    int wave = (blockIdx.x * blockDim.x + threadIdx.x) >> 6;
    int nwaves = (gridDim.x * blockDim.x) >> 6;
    for (int n = wave; n < n_nodes; n += nwaves) {
        const float* hr = h + (size_t)n * K;
        float acc = 0.f;
#pragma unroll
        for (int k = 0; k < K; k++) acc += hr[k] * wcol[k];
        xw[(size_t)n * HID + f] = (half_t)acc;
    }
}

// ------- MFMA GEMM: fp16 interleaved h rows in, fused BN+ReLU, xw rows out --
__global__ __launch_bounds__(256) void gemm_bn_mfma_kernel(const half_t* __restrict__ h,
                                                           const float* __restrict__ W,
                                                           const float* __restrict__ stats,
                                                           const float* __restrict__ gamma,
                                                           const float* __restrict__ beta,
                                                           half_t* __restrict__ xw, int n_nodes) {
    __shared__ float sc_s[HID], sh_s[HID];
    if (threadIdx.x < 64) {
        float mean = stats[threadIdx.x] * (1.0f / N_NODES);
        float var = stats[64 + threadIdx.x] * (1.0f / N_NODES) - mean * mean;
        float sc = gamma[threadIdx.x] * rsqrtf(var + EPS);
        sc_s[threadIdx.x] = sc;
        sh_s[threadIdx.x] = beta[threadIdx.x] - mean * sc;
    }
    __syncthreads();
    int lane = threadIdx.x & 63;
    int col16 = lane & 15;
    int quad = lane >> 4;

    float scA[2][8], shA[2][8];
#pragma unroll
    for (int kh = 0; kh < 2; kh++)
#pragma unroll
        for (int j = 0; j < 8; j++) {
            int k = kh * 32 + quad * 8 + j;
            scA[kh][j] = sc_s[k];
            shA[kh][j] = sh_s[k];
        }

    half8 bfrag[4][2];
#pragma unroll
    for (int t = 0; t < 4; t++)
#pragma unroll
        for (int kh = 0; kh < 2; kh++)
#pragma unroll
            for (int j = 0; j < 8; j++) {
                int k = kh * 32 + quad * 8 + j;
                bfrag[t][kh][j] = (half_t)W[k * HID + t * 16 + col16];
            }

    int wave = (blockIdx.x * blockDim.x + threadIdx.x) >> 6;
    int nwaves = (gridDim.x * blockDim.x) >> 6;
    int ntiles = n_nodes >> 4;
    for (int tIdx = wave; tIdx < ntiles; tIdx += nwaves) {
        int n0 = tIdx << 4;
        half8 afrag[2];
#pragma unroll
        for (int kh = 0; kh < 2; kh++) {
            const half_t* hp = h + (size_t)(n0 + col16) * HID + kh * 32 + quad * 8;
            half8 raw = *(const half8*)hp;
#pragma unroll
            for (int j = 0; j < 8; j++) {
                float v = (float)raw[j] * scA[kh][j] + shA[kh][j];
                afrag[kh][j] = (half_t)fmaxf(v, 0.f);
            }
        }
        f32x4 acc[4];
#pragma unroll
        for (int t = 0; t < 4; t++) {
            f32x4 z = {0.f, 0.f, 0.f, 0.f};
            acc[t] = __builtin_amdgcn_mfma_f32_16x16x32_f16(afrag[0], bfrag[t][0], z, 0, 0, 0);
            acc[t] = __builtin_amdgcn_mfma_f32_16x16x32_f16(afrag[1], bfrag[t][1], acc[t], 0, 0, 0);
        }
#pragma unroll
        for (int t = 0; t < 4; t++)
#pragma unroll
            for (int r = 0; r < 4; r++) {
                int rowi = n0 + quad * 4 + r;
                xw[(size_t)rowi * HID + t * 16 + col16] = (half_t)acc[t][r];
            }
    }
}

// ------- CSR gather: WAVE per node, lane = feature, full 128-B row loads ----
// One gather instruction = one edge = one fully-used 128-B coalesced row.
// Mult-4 padding -> branch-free 16-edge chunks (16 row-gathers in flight) +
// <=3 four-edge tail steps. Metadata loads wave-uniform (HW broadcast).
template <bool LAST>
__global__ __launch_bounds__(256) void gather_stats_kernel(const int* __restrict__ ptrS,
                                                           const int* __restrict__ perm,
                                                           const unsigned int* __restrict__ srcoff,
                                                           const half_t* __restrict__ normh,
                                                           const half_t* __restrict__ xw,
                                                           const float* __restrict__ dinv,
                                                           const float* __restrict__ b,
                                                           half_t* __restrict__ hp,
                                                           float* __restrict__ hf,
                                                           float* __restrict__ stats,
                                                           int n_nodes) {
    int lane = threadIdx.x & 63;     // = feature f
    int waveId = (blockIdx.x * blockDim.x + threadIdx.x) >> 6;
    int nwaves = (gridDim.x * blockDim.x) >> 6;

    const char* xgc = (const char*)xw;
    unsigned int loff = (unsigned int)(lane * 2);
    const unsigned int* np = (const unsigned int*)normh;
    float bf = b[lane];

    float s = 0.f, s2 = 0.f;
    for (int i = waveId; i < n_nodes; i += nwaves) {
        int node = perm[i];
        int j = ptrS[i];
        int cend = ptrS[i + 1];
        float a0 = 0.f, a1 = 0.f, a2 = 0.f, a3 = 0.f;
        float a4 = 0.f, a5 = 0.f, a6 = 0.f, a7 = 0.f;
        for (; j + 16 <= cend; j += 16) {   // 16 independent row-gathers in flight
            u32x4 s0 = *(const u32x4*)(srcoff + j);
            u32x4 s1 = *(const u32x4*)(srcoff + j + 4);
            u32x4 s2v = *(const u32x4*)(srcoff + j + 8);
            u32x4 s3 = *(const u32x4*)(srcoff + j + 12);
            int jh = j >> 1;
            u32x4 nA = *(const u32x4*)(np + jh);
            u32x4 nB = *(const u32x4*)(np + jh + 4);
            float x0 = (float)*(const __half*)(xgc + (s0.x + loff));
            float x1 = (float)*(const __half*)(xgc + (s0.y + loff));
            float x2 = (float)*(const __half*)(xgc + (s0.z + loff));
            float x3 = (float)*(const __half*)(xgc + (s0.w + loff));
            float x4 = (float)*(const __half*)(xgc + (s1.x + loff));
            float x5 = (float)*(const __half*)(xgc + (s1.y + loff));
            float x6 = (float)*(const __half*)(xgc + (s1.z + loff));
            float x7 = (float)*(const __half*)(xgc + (s1.w + loff));
            float x8 = (float)*(const __half*)(xgc + (s2v.x + loff));
            float x9 = (float)*(const __half*)(xgc + (s2v.y + loff));
            float xA = (float)*(const __half*)(xgc + (s2v.z + loff));
            float xB = (float)*(const __half*)(xgc + (s2v.w + loff));
            float xC = (float)*(const __half*)(xgc + (s3.x + loff));
            float xD = (float)*(const __half*)(xgc + (s3.y + loff));
            float xE = (float)*(const __half*)(xgc + (s3.z + loff));
            float xF = (float)*(const __half*)(xgc + (s3.w + loff));
            __half2 n0h = u32_as_half2(nA.x), n1h = u32_as_half2(nA.y);
            __half2 n2h = u32_as_half2(nA.z), n3h = u32_as_half2(nA.w);
            __half2 n4h = u32_as_half2(nB.x), n5h = u32_as_half2(nB.y);
            __half2 n6h = u32_as_half2(nB.z), n7h = u32_as_half2(nB.w);
            a0 += __low2float(n0h) * x0;  a1 += __high2float(n0h) * x1;
            a2 += __low2float(n1h) * x2;  a3 += __high2float(n1h) * x3;
            a4 += __low2float(n2h) * x4;  a5 += __high2float(n2h) * x5;
            a6 += __low2float(n3h) * x6;  a7 += __high2float(n3h) * x7;
            a0 += __low2float(n4h) * x8;  a1 += __high2float(n4h) * x9;
            a2 += __low2float(n5h) * xA;  a3 += __high2float(n5h) * xB;
            a4 += __low2float(n6h) * xC;  a5 += __high2float(n6h) * xD;
            a6 += __low2float(n7h) * xE;  a7 += __high2float(n7h) * xF;
        }
        for (; j < cend; j += 4) {          // tail: <=3 four-edge steps
            u32x4 s0 = *(const u32x4*)(srcoff + j);
            u32x2 n0 = *(const u32x2*)(np + (j >> 1));
            float x0 = (float)*(const __half*)(xgc + (s0.x + loff));
            float x1 = (float)*(const __half*)(xgc + (s0.y + loff));
            float x2 = (float)*(const __half*)(xgc + (s0.z + loff));
            float x3 = (float)*(const __half*)(xgc + (s0.w + loff));
            __half2 n0h = u32_as_half2(n0.x), n1h = u32_as_half2(n0.y);
            a0 += __low2float(n0h) * x0;  a1 += __high2float(n0h) * x1;
            a2 += __low2float(n1h) * x2;  a3 += __high2float(n1h) * x3;
        }
        float accf = (((a0 + a1) + (a2 + a3)) + ((a4 + a5) + (a6 + a7)));
        float di = dinv[node];
        float xself = (float)*(const __half*)(xgc + (((unsigned int)node << 7) + loff));
        float v = accf + di * di * xself + bf;
        if (LAST)
            hf[(size_t)node * HID + lane] = v;
        else
            hp[(size_t)node * HID + lane] = (half_t)v;
        s += v;
        s2 += v * v;
    }
    __shared__ float ls[256], ls2[256];
    ls[threadIdx.x] = s;
    ls2[threadIdx.x] = s2;
    __syncthreads();
    if (threadIdx.x < 64) {
        float a = ls[threadIdx.x] + ls[threadIdx.x + 64] + ls[threadIdx.x + 128] + ls[threadIdx.x + 192];
        float aa = ls2[threadIdx.x] + ls2[threadIdx.x + 64] + ls2[threadIdx.x + 128] + ls2[threadIdx.x + 192];
        atomicAdd(&stats[threadIdx.x], a);
        atomicAdd(&stats[64 + threadIdx.x], aa);
    }
}

// ---------------- layer 3: BN + ReLU + write node_embs + segment-sum --------
__global__ __launch_bounds__(256) void bn_relu_seg_kernel(float* __restrict__ h,
                                                          const float* __restrict__ stats,
                                                          const float* __restrict__ gamma,
                                                          const float* __restrict__ beta,
                                                          const int* __restrict__ batch,
                                                          float* __restrict__ gemb,
                                                          int n_nodes) {
    int g = blockIdx.x * blockDim.x + threadIdx.x;
    int f = g & 63;
    int wave = g >> 6;
    int nwaves = (gridDim.x * blockDim.x) >> 6;
    int chunk = (n_nodes + nwaves - 1) / nwaves;
    int n0 = wave * chunk;
    int n1 = n0 + chunk;
    if (n1 > n_nodes) n1 = n_nodes;
    if (n0 >= n_nodes) return;
    float mean = stats[f] * (1.0f / N_NODES);
    float var = stats[64 + f] * (1.0f / N_NODES) - mean * mean;
    float sc = gamma[f] * rsqrtf(var + EPS);
    float sh = beta[f] - mean * sc;
    int curg = batch[n0];
    float racc = 0.f;
    for (int n = n0; n < n1; n++) {
        int bg = batch[n];
        if (bg != curg) {
            atomicAdd(&gemb[(size_t)curg * HID + f], racc);
            racc = 0.f;
            curg = bg;
        }
        size_t idx = (size_t)n * HID + f;
        float v = h[idx] * sc + sh;
        v = fmaxf(v, 0.f);
        h[idx] = v;
        racc += v;
    }
    atomicAdd(&gemb[(size_t)curg * HID + f], racc);
}

__global__ __launch_bounds__(256) void final_kernel(const float* __restrict__ gemb,
                                                    const float* __restrict__ fcW,
                                                    const float* __restrict__ fcb,
                                                    float* __restrict__ out) {
    int g = blockIdx.x * blockDim.x + threadIdx.x;
    if (g >= N_GRAPHS * N_CLS) return;
    int gr = g >> 1, c = g & 1;
    float acc = fcb[c];
#pragma unroll
    for (int k = 0; k < HID; k++) acc += gemb[gr * HID + k] * fcW[k * N_CLS + c];
    out[g] = acc;
}

// ---------------- launch ----------------

extern "C" void kernel_launch(void* const* d_in, const int* in_sizes, int n_in,
                              void* d_out, int out_size, void* d_ws, size_t ws_size,
                              hipStream_t stream) {
    const float* x    = (const float*)d_in[0];
    const int*   ei   = (const int*)d_in[1];
    const int*   batch= (const int*)d_in[2];
    const float* ew   = (const float*)d_in[3];
    const float* W1   = (const float*)d_in[4];
    const float* b1   = (const float*)d_in[5];
    const float* W2   = (const float*)d_in[6];
    const float* b2   = (const float*)d_in[7];
    const float* W3   = (const float*)d_in[8];
    const float* b3   = (const float*)d_in[9];
    const float* g1   = (const float*)d_in[10];
    const float* bt1  = (const float*)d_in[11];
    const float* g2   = (const float*)d_in[12];
    const float* bt2  = (const float*)d_in[13];
    const float* g3   = (const float*)d_in[14];
    const float* bt3  = (const float*)d_in[15];
    const float* fcW  = (const float*)d_in[16];
    const float* fcb  = (const float*)d_in[17];

    const int* row = ei;
    const int* col = ei + N_EDGES;

    // d_out layout: out [2048*2] | node_embs [100000*64] | graph_emb [2048*64]
    float* out_head  = (float*)d_out;
    float* node_embs = out_head + N_GRAPHS * N_CLS;
    float* gemb      = node_embs + (size_t)N_NODES * HID;

    // ws layout with lifetime overlays:
    //  R0 (12.8 MB): xwh rows (node x 64 fp16)
    //  R1 (12.8 MB): EA (CSR build) -> h fp16 rows (written after EA dead)
    //  R2 (11.4 MB): srcoff u32[EMAX4] + normh f16[EMAX4]
    char* bse = (char*)d_ws;
    half_t* xwh = (half_t*)bse;                        // R0
    char* r1 = bse + (size_t)N_NODES * HID * 2;        // 12.8e6 (16-aligned)
    int2*   EA  = (int2*)r1;                           // R1
    half_t* hpl = (half_t*)r1;                         // h fp16 rows
    char* r2 = r1 + (size_t)N_NODES * HID * 2;
    unsigned int* srcoff = (unsigned int*)r2;          // EMAX4 u32 (7.6e6 B)
    half_t* normh = (half_t*)(srcoff + EMAX4);         // EMAX4 f16 (3.8e6 B)
    char* r3 = r2 + (size_t)EMAX4 * 6;
    float* dinv  = (float*)r3;                         // 400 KB
    float* stats3 = dinv + N_NODES;                    // 3 x 128 floats
    int*   ptr   = (int*)(stats3 + 384);               // (N+1) ints
    int*   histG = ptr + N_NODES + 1;                  // NBUCK*ABLOCKS
    int*   bsumA = histG + NBUCK * ABLOCKS;            // NBUCK
    int*   histD = bsumA + NBUCK + 4;                  // 256*NBLK2
    int*   rowTot = histD + 256 * NBLK2;               // 256
    int*   nodeExcl = rowTot + 256;                    // 256
    int*   edgeExcl = nodeExcl + 256;                  // 256
    int*   perm   = edgeExcl + 256;                    // N
    int*   newbase= perm + N_NODES;                    // N
    int*   ptrS   = newbase + N_NODES;                 // N+1

    const int B   = 256;
    const int gGS = 1024;   // grid-stride
    const int gGA = 2048;   // gather (8192 waves)

    // ---- CSR build: LDS counting sort, zero global atomics ----
    histA_kernel<<<ABLOCKS, B, 0, stream>>>(col, histG);
    scanS1_kernel<<<NBUCK, B, 0, stream>>>(histG, bsumA);
    topscan_kernel<<<1, 512, 0, stream>>>(bsumA, NBUCK);
    scanS3_kernel<<<NBUCK, B, 0, stream>>>(histG, bsumA, ptr);
    scatterA_kernel<<<ABLOCKS, B, 0, stream>>>(row, col, ew, histG, EA);
    bucketA_kernel<<<NBUCK, B, 0, stream>>>(EA, bsumA, ptr, dinv);

    // ---- degree sort of nodes (mult-of-4-padded edge layout) ----
    histD_kernel<<<NBLK2, B, 0, stream>>>(ptr, histD);
    scanD1_kernel<<<256, 128, 0, stream>>>(histD, rowTot);
    topscanD_kernel<<<1, 256, 0, stream>>>(rowTot, nodeExcl, edgeExcl, ptrS);
    scanD3_kernel<<<256, 128, 0, stream>>>(histD, nodeExcl);
    scatterD_kernel<<<NBLK2, B, 0, stream>>>(ptr, histD, nodeExcl, edgeExcl,
                                             perm, ptrS, newbase);
    hipMemsetAsync(srcoff, 0, (size_t)EMAX4 * 6, stream);   // padding -> 0
    hipMemsetAsync(stats3, 0, 384 * sizeof(float), stream); // all 3 layers' stats
    hipMemsetAsync(gemb, 0, (size_t)N_GRAPHS * HID * sizeof(float), stream);
    bucketB_kernel<<<NBUCK, B, 0, stream>>>(EA, bsumA, newbase, dinv, srcoff, normh);

    float* h3 = node_embs;  // raw (pre-BN) layer-3 activation; ends as output

    // ---- layer 1 ----
    gemm_kernel<IN_F><<<gGS, B, 0, stream>>>(x, W1, xwh, N_NODES);
    gather_stats_kernel<false><<<gGA, B, 0, stream>>>(ptrS, perm, srcoff, normh, xwh,
                                                      dinv, b1, hpl, h3, stats3, N_NODES);

    // ---- layer 2 (BN1+ReLU fused into MFMA GEMM; fp16 h rows in) ----
    gemm_bn_mfma_kernel<<<gGS, B, 0, stream>>>(hpl, W2, stats3, g1, bt1, xwh, N_NODES);
    gather_stats_kernel<false><<<gGA, B, 0, stream>>>(ptrS, perm, srcoff, normh, xwh,
                                                      dinv, b2, hpl, h3, stats3 + 128, N_NODES);

    // ---- layer 3 (BN2+ReLU fused into MFMA GEMM) ----
    gemm_bn_mfma_kernel<<<gGS, B, 0, stream>>>(hpl, W3, stats3 + 128, g2, bt2, xwh, N_NODES);
    gather_stats_kernel<true><<<gGA, B, 0, stream>>>(ptrS, perm, srcoff, normh, xwh,
                                                     dinv, b3, hpl, h3, stats3 + 256, N_NODES);

    // ---- BN3 + ReLU + node_embs + segment-sum ----
    bn_relu_seg_kernel<<<gGS, B, 0, stream>>>(h3, stats3 + 256, g3, bt3, batch, gemb, N_NODES);

    // ---- readout ----
    final_kernel<<<(N_GRAPHS * N_CLS + B - 1) / B, B, 0, stream>>>(gemb, fcW, fcb, out_head);
}

// Round 15
// 411.352 us; speedup vs baseline: 1.2316x; 1.2316x over previous
//
#include <hip/hip_runtime.h>
#include <hip/hip_fp16.h>

#define N_NODES 100000
#define N_EDGES 1600000
#define EMAX2   1700000                 // even-padded edge capacity
#define N_GRAPHS 2048
#define HID 64
#define IN_F 14
#define N_CLS 2
#define EPS 1e-5f

#define BSHIFT 9
#define NBUCK 196                       // ceil(100000 / 512)
#define ABLOCKS 256
#define CHUNK (N_EDGES / ABLOCKS)       // 6250, exact

#define NBLK2 128                       // node-sort blocks
#define NCHUNK2 ((N_NODES + NBLK2 - 1) / NBLK2)  // 782

typedef _Float16 half_t;
typedef _Float16 half8 __attribute__((ext_vector_type(8)));
typedef float f32x4 __attribute__((ext_vector_type(4)));

#define GSTRIDE ((size_t)N_NODES * 16)  // halves per feature-group plane

// ============ CSR build, atomic-free (global) two-level counting sort ========

__global__ __launch_bounds__(256) void histA_kernel(const int* __restrict__ col,
                                                    int* __restrict__ histG) {
    __shared__ int hl[NBUCK];
    for (int i = threadIdx.x; i < NBUCK; i += 256) hl[i] = 0;
    __syncthreads();
    int e0 = blockIdx.x * CHUNK;
    for (int e = e0 + threadIdx.x; e < e0 + CHUNK; e += 256)
        atomicAdd(&hl[col[e] >> BSHIFT], 1);
    __syncthreads();
    for (int i = threadIdx.x; i < NBUCK; i += 256)
        histG[i * ABLOCKS + blockIdx.x] = hl[i];
}

__global__ __launch_bounds__(256) void scanS1_kernel(const int* __restrict__ histG,
                                                     int* __restrict__ bsumA) {
    __shared__ int ls[256];
    ls[threadIdx.x] = histG[blockIdx.x * 256 + threadIdx.x];
    __syncthreads();
    for (int off = 128; off > 0; off >>= 1) {
        if (threadIdx.x < off) ls[threadIdx.x] += ls[threadIdx.x + off];
        __syncthreads();
    }
    if (threadIdx.x == 0) bsumA[blockIdx.x] = ls[0];
}

__global__ __launch_bounds__(512) void topscan_kernel(int* __restrict__ bsum, int nb) {
    __shared__ int ls[512];
    int t = threadIdx.x;
    int v = (t < nb) ? bsum[t] : 0;
    ls[t] = v;
    __syncthreads();
    for (int off = 1; off < 512; off <<= 1) {
        int x = ls[t];
        if (t >= off) x += ls[t - off];
        __syncthreads();
        ls[t] = x;
        __syncthreads();
    }
    if (t < nb) bsum[t] = ls[t] - v;  // exclusive
}

__global__ __launch_bounds__(256) void scanS3_kernel(int* __restrict__ histG,
                                                     const int* __restrict__ bsumA,
                                                     int* __restrict__ ptr) {
    __shared__ int ls[256];
    int idx = blockIdx.x * 256 + threadIdx.x;
    int v = histG[idx];
    ls[threadIdx.x] = v;
    __syncthreads();
    for (int off = 1; off < 256; off <<= 1) {
        int x = ls[threadIdx.x];
        if (threadIdx.x >= off) x += ls[threadIdx.x - off];
        __syncthreads();
        ls[threadIdx.x] = x;
        __syncthreads();
    }
    histG[idx] = ls[threadIdx.x] - v + bsumA[blockIdx.x];
    if (blockIdx.x == 0 && threadIdx.x == 0) ptr[N_NODES] = N_EDGES;
}

__global__ __launch_bounds__(256) void scatterA_kernel(const int* __restrict__ row,
                                                       const int* __restrict__ col,
                                                       const float* __restrict__ w,
                                                       const int* __restrict__ histG,
                                                       int2* __restrict__ EA) {
    __shared__ int cur[NBUCK];
    for (int i = threadIdx.x; i < NBUCK; i += 256)
        cur[i] = histG[i * ABLOCKS + blockIdx.x];
    __syncthreads();
    int e0 = blockIdx.x * CHUNK;
    for (int e = e0 + threadIdx.x; e < e0 + CHUNK; e += 256) {
        int c = col[e];
        int r = row[e];
        int fx = (int)__float2uint_rn(w[e] * 8192.0f);   // 15-bit fixed, exact for w=1
        int pos = atomicAdd(&cur[c >> BSHIFT], 1);        // LDS atomic
        EA[pos] = make_int2(r, (fx << 17) | c);
    }
}

// bucketA: per-bucket dense hist+scan -> ptr (unpadded CSR base), dinv
__global__ __launch_bounds__(256) void bucketA_kernel(const int2* __restrict__ EA,
                                                      const int* __restrict__ bsumA,
                                                      int* __restrict__ ptr,
                                                      float* __restrict__ dinv) {
    __shared__ int hist[512], wsum[512];
    int b = blockIdx.x;
    int beg = bsumA[b];
    int end = (b == NBUCK - 1) ? N_EDGES : bsumA[b + 1];
    int i0 = threadIdx.x, i1 = threadIdx.x + 256;
    hist[i0] = 0; hist[i1] = 0;
    wsum[i0] = 0; wsum[i1] = 0;
    __syncthreads();
    for (int e = beg + threadIdx.x; e < end; e += 256) {
        int2 ed = EA[e];
        int c9 = ed.y & 511;
        atomicAdd(&hist[c9], 1);
        atomicAdd(&wsum[c9], (int)((unsigned int)ed.y >> 17));
    }
    __syncthreads();
    int cnt0 = hist[i0], cnt1 = hist[i1];
    for (int off = 1; off < 512; off <<= 1) {
        int v0 = hist[i0], v1 = hist[i1];
        int a0 = (i0 >= off) ? hist[i0 - off] : 0;
        int a1 = (i1 >= off) ? hist[i1 - off] : 0;
        __syncthreads();
        hist[i0] = v0 + a0;
        hist[i1] = v1 + a1;
        __syncthreads();
    }
    int excl0 = hist[i0] - cnt0, excl1 = hist[i1] - cnt1;
    int col0 = (b << BSHIFT) + i0, col1 = (b << BSHIFT) + i1;
    if (col0 < N_NODES) {
        ptr[col0] = beg + excl0;
        dinv[col0] = rsqrtf(1.0f + (float)wsum[i0] * (1.0f / 8192.0f));
    }
    if (col1 < N_NODES) {
        ptr[col1] = beg + excl1;
        dinv[col1] = rsqrtf(1.0f + (float)wsum[i1] * (1.0f / 8192.0f));
    }
}

// ============ node degree sort (even-padded edge layout) =====================

__global__ __launch_bounds__(256) void histD_kernel(const int* __restrict__ ptr,
                                                    int* __restrict__ histD) {
    __shared__ int hl[2048];
    for (int i = threadIdx.x; i < 2048; i += 256) hl[i] = 0;
    __syncthreads();
    int n0 = blockIdx.x * NCHUNK2;
    int n1 = n0 + NCHUNK2; if (n1 > N_NODES) n1 = N_NODES;
    for (int n = n0 + threadIdx.x; n < n1; n += 256) {
        int d = ptr[n + 1] - ptr[n];
        if (d > 255) d = 255;
        atomicAdd(&hl[((threadIdx.x & 7) << 8) + d], 1);
    }
    __syncthreads();
    int s = 0;
#pragma unroll
    for (int c = 0; c < 8; c++) s += hl[(c << 8) + threadIdx.x];
    histD[threadIdx.x * NBLK2 + blockIdx.x] = s;
}

__global__ __launch_bounds__(128) void scanD1_kernel(const int* __restrict__ histD,
                                                     int* __restrict__ rowTot) {
    __shared__ int ls[128];
    ls[threadIdx.x] = histD[blockIdx.x * NBLK2 + threadIdx.x];
    __syncthreads();
    for (int off = 64; off > 0; off >>= 1) {
        if (threadIdx.x < off) ls[threadIdx.x] += ls[threadIdx.x + off];
        __syncthreads();
    }
    if (threadIdx.x == 0) rowTot[blockIdx.x] = ls[0];
}

// D3: bins scanned with node counts and EVEN-padded edge counts
__global__ __launch_bounds__(256) void topscanD_kernel(const int* __restrict__ rowTot,
                                                       int* __restrict__ nodeExcl,
                                                       int* __restrict__ edgeExcl,
                                                       int* __restrict__ ptrS) {
    __shared__ int a[256], b[256];
    int t = threadIdx.x;
    int cnt = rowTot[t];
    int dpad = (t + 1) & ~1;
    int ec = cnt * dpad;
    a[t] = cnt; b[t] = ec;
    __syncthreads();
    for (int off = 1; off < 256; off <<= 1) {
        int va = a[t], vb = b[t];
        if (t >= off) { va += a[t - off]; vb += b[t - off]; }
        __syncthreads();
        a[t] = va; b[t] = vb;
        __syncthreads();
    }
    nodeExcl[t] = a[t] - cnt;
    edgeExcl[t] = b[t] - ec;
    if (t == 255) ptrS[N_NODES] = b[255];   // total padded edges
}

__global__ __launch_bounds__(128) void scanD3_kernel(int* __restrict__ histD,
                                                     const int* __restrict__ nodeExcl) {
    __shared__ int ls[128];
    int idx = blockIdx.x * NBLK2 + threadIdx.x;
    int v = histD[idx];
    ls[threadIdx.x] = v;
    __syncthreads();
    for (int off = 1; off < 128; off <<= 1) {
        int x = ls[threadIdx.x];
        if (threadIdx.x >= off) x += ls[threadIdx.x - off];
        __syncthreads();
        ls[threadIdx.x] = x;
        __syncthreads();
    }
    histD[idx] = ls[threadIdx.x] - v + nodeExcl[blockIdx.x];
}

__global__ __launch_bounds__(256) void scatterD_kernel(const int* __restrict__ ptr,
                                                       const int* __restrict__ histD,
                                                       const int* __restrict__ nodeExcl,
                                                       const int* __restrict__ edgeExcl,
                                                       int* __restrict__ perm,
                                                       int* __restrict__ ptrS,
                                                       int* __restrict__ newbase) {
    __shared__ int cur[256];
    cur[threadIdx.x] = histD[threadIdx.x * NBLK2 + blockIdx.x];
    __syncthreads();
    int n0 = blockIdx.x * NCHUNK2;
    int n1 = n0 + NCHUNK2; if (n1 > N_NODES) n1 = N_NODES;
    for (int n = n0 + threadIdx.x; n < n1; n += 256) {
        int d = ptr[n + 1] - ptr[n];
        if (d > 255) d = 255;
        int dpad = (d + 1) & ~1;
        int pos = atomicAdd(&cur[d], 1);                  // LDS atomic
        int ebase = edgeExcl[d] + (pos - nodeExcl[d]) * dpad;
        perm[pos] = n;
        ptrS[pos] = ebase;
        newbase[n] = ebase;
    }
}

// bucketB: scatter EA directly to final split arrays (srcoff u32, norm fp16)
// at even-padded degree-sorted positions. Padding slots pre-zeroed by memset.
__global__ __launch_bounds__(256) void bucketB_kernel(const int2* __restrict__ EA,
                                                      const int* __restrict__ bsumA,
                                                      const int* __restrict__ newbase,
                                                      const float* __restrict__ dinv,
                                                      unsigned int* __restrict__ srcoff,
                                                      half_t* __restrict__ normh) {
    __shared__ int cur[512];
    int b = blockIdx.x;
    int beg = bsumA[b];
    int end = (b == NBUCK - 1) ? N_EDGES : bsumA[b + 1];
    int i0 = threadIdx.x, i1 = threadIdx.x + 256;
    int col0 = (b << BSHIFT) + i0, col1 = (b << BSHIFT) + i1;
    cur[i0] = (col0 < N_NODES) ? newbase[col0] : 0;
    cur[i1] = (col1 < N_NODES) ? newbase[col1] : 0;
    __syncthreads();
    for (int e = beg + threadIdx.x; e < end; e += 256) {
        int2 ed = EA[e];
        int c = ed.y & 0x1ffff;
        float w = (float)((unsigned int)ed.y >> 17) * (1.0f / 8192.0f);
        float nrm = dinv[ed.x] * w * dinv[c];
        int pos = atomicAdd(&cur[c & 511], 1);            // LDS atomic
        srcoff[pos] = (unsigned int)ed.x << 5;            // byte offset into plane
        normh[pos] = (half_t)nrm;
    }
}

// ---------------- layer-1 GEMM (K=14, VALU), grouped store ----------------

template <int K>
__global__ __launch_bounds__(256) void gemm_kernel(const float* __restrict__ h,
                                                   const float* __restrict__ W,
                                                   half_t* __restrict__ xw, int n_nodes) {
    int f = threadIdx.x & 63;
    float wcol[K];
#pragma unroll
    for (int k = 0; k < K; k++) wcol[k] = W[k * HID + f];
    half_t* xg = xw + (size_t)(f >> 4) * GSTRIDE + (f & 15);
    int wave = (blockIdx.x * blockDim.x + threadIdx.x) >> 6;
    int nwaves = (gridDim.x * blockDim.x) >> 6;
    for (int n = wave; n < n_nodes; n += nwaves) {
        const float* hr = h + (size_t)n * K;
        float acc = 0.f;
#pragma unroll
        for (int k = 0; k < K; k++) acc += hr[k] * wcol[k];
        xg[(size_t)n * 16] = (half_t)acc;
    }
}

// ------- MFMA GEMM: input = fp16 h PLANES, fused BN+ReLU, grouped store ------
__global__ __launch_bounds__(256) void gemm_bn_mfma_kernel(const half_t* __restrict__ h,
                                                           const float* __restrict__ W,
                                                           const float* __restrict__ stats,
                                                           const float* __restrict__ gamma,
                                                           const float* __restrict__ beta,
                                                           half_t* __restrict__ xw, int n_nodes) {
    __shared__ float sc_s[HID], sh_s[HID];
    if (threadIdx.x < 64) {
        float mean = stats[threadIdx.x] * (1.0f / N_NODES);
        float var = stats[64 + threadIdx.x] * (1.0f / N_NODES) - mean * mean;
        float sc = gamma[threadIdx.x] * rsqrtf(var + EPS);
        sc_s[threadIdx.x] = sc;
        sh_s[threadIdx.x] = beta[threadIdx.x] - mean * sc;
    }
    __syncthreads();
    int lane = threadIdx.x & 63;
    int col16 = lane & 15;
    int quad = lane >> 4;

    float scA[2][8], shA[2][8];
#pragma unroll
    for (int kh = 0; kh < 2; kh++)
#pragma unroll
        for (int j = 0; j < 8; j++) {
            int k = kh * 32 + quad * 8 + j;
            scA[kh][j] = sc_s[k];
            shA[kh][j] = sh_s[k];
        }

    half8 bfrag[4][2];
#pragma unroll
    for (int t = 0; t < 4; t++)
#pragma unroll
        for (int kh = 0; kh < 2; kh++)
#pragma unroll
            for (int j = 0; j < 8; j++) {
                int k = kh * 32 + quad * 8 + j;
                bfrag[t][kh][j] = (half_t)W[k * HID + t * 16 + col16];
            }

    int wave = (blockIdx.x * blockDim.x + threadIdx.x) >> 6;
    int nwaves = (gridDim.x * blockDim.x) >> 6;
    int ntiles = n_nodes >> 4;
    for (int tIdx = wave; tIdx < ntiles; tIdx += nwaves) {
        int n0 = tIdx << 4;
        half8 afrag[2];
#pragma unroll
        for (int kh = 0; kh < 2; kh++) {
            int k0 = kh * 32 + quad * 8;
            const half_t* hp = h + (size_t)(k0 >> 4) * GSTRIDE
                                 + (size_t)(n0 + col16) * 16 + (k0 & 15);
            half8 raw = *(const half8*)hp;
#pragma unroll
            for (int j = 0; j < 8; j++) {
                float v = (float)raw[j] * scA[kh][j] + shA[kh][j];
                afrag[kh][j] = (half_t)fmaxf(v, 0.f);
            }
        }
        f32x4 acc[4];
#pragma unroll
        for (int t = 0; t < 4; t++) {
            f32x4 z = {0.f, 0.f, 0.f, 0.f};
            acc[t] = __builtin_amdgcn_mfma_f32_16x16x32_f16(afrag[0], bfrag[t][0], z, 0, 0, 0);
            acc[t] = __builtin_amdgcn_mfma_f32_16x16x32_f16(afrag[1], bfrag[t][1], acc[t], 0, 0, 0);
        }
#pragma unroll
        for (int t = 0; t < 4; t++) {
            half_t* xg = xw + (size_t)t * GSTRIDE;
#pragma unroll
            for (int r = 0; r < 4; r++) {
                int rowi = n0 + quad * 4 + r;
                xg[(size_t)rowi * 16 + col16] = (half_t)acc[t][r];
            }
        }
    }
}

// ------- feature-grouped CSR gather: quad per sorted node, paired fp16 math --
// (r11's proven 57.6 µs structure.) Always writes fp16 planes.
__global__ __launch_bounds__(256) void gather_stats_kernel(const int* __restrict__ ptrS,
                                                           const int* __restrict__ perm,
                                                           const unsigned int* __restrict__ srcoff,
                                                           const unsigned int* __restrict__ normu,
                                                           const half_t* __restrict__ xw,
                                                           const float* __restrict__ dinv,
                                                           const float* __restrict__ b,
                                                           half_t* __restrict__ hp,
                                                           float* __restrict__ stats,
                                                           int n_nodes) {
    int g = (blockIdx.x & 7) >> 1;                           // feature group 0..3
    int grank = ((blockIdx.x >> 3) << 1) | (blockIdx.x & 1); // rank within group
    int lane16 = threadIdx.x & 15;
    int quadLocal = threadIdx.x >> 4;                        // 0..15
    int quadId = grank * 16 + quadLocal;
    int nquads = (gridDim.x >> 2) * 16;

    const half_t* xg = xw + (size_t)g * GSTRIDE;
    const char* xgc = (const char*)xg;
    unsigned int loff = (unsigned int)(lane16 * 2);
    half_t* hpg = hp + (size_t)g * GSTRIDE;
    int f = g * 16 + lane16;
    float bf = b[f];
    int base = ((threadIdx.x & 63) >> 4) * 16;               // quad's shfl window

    float s = 0.f, s2 = 0.f;
    for (int i = quadId; i < n_nodes; i += nquads) {
        int node = perm[i];
        int beg = ptrS[i];
        int c = ptrS[i + 1] - beg;                           // even (padded)
        __half2 acc0 = __float2half2_rn(0.f);
        __half2 acc1 = __float2half2_rn(0.f);
        for (int j0 = 0; j0 < c; j0 += 16) {
            int m = c - j0;
            if (m > 16) m = 16;
            int pairs = m >> 1;
            int ev = 0, nv = 0;
            if (lane16 < m) ev = (int)srcoff[beg + j0 + lane16];
            if (lane16 < pairs) nv = (int)normu[((beg + j0) >> 1) + lane16];
            int p = 0;
            for (; p + 2 <= pairs; p += 2) {
                unsigned int u0 = (unsigned int)__shfl(ev, base + 2 * p);
                unsigned int u1 = (unsigned int)__shfl(ev, base + 2 * p + 1);
                unsigned int u2 = (unsigned int)__shfl(ev, base + 2 * p + 2);
                unsigned int u3 = (unsigned int)__shfl(ev, base + 2 * p + 3);
                unsigned int nd0 = (unsigned int)__shfl(nv, base + p);
                unsigned int nd1 = (unsigned int)__shfl(nv, base + p + 1);
                __half h0 = *(const __half*)(xgc + (u0 + loff));
                __half h1 = *(const __half*)(xgc + (u1 + loff));
                __half h2 = *(const __half*)(xgc + (u2 + loff));
                __half h3 = *(const __half*)(xgc + (u3 + loff));
                __half2 n01 = *(__half2*)&nd0;
                __half2 n23 = *(__half2*)&nd1;
                acc0 = __hfma2(n01, __halves2half2(h0, h1), acc0);
                acc1 = __hfma2(n23, __halves2half2(h2, h3), acc1);
            }
            if (p < pairs) {
                unsigned int u0 = (unsigned int)__shfl(ev, base + 2 * p);
                unsigned int u1 = (unsigned int)__shfl(ev, base + 2 * p + 1);
                unsigned int nd0 = (unsigned int)__shfl(nv, base + p);
                __half h0 = *(const __half*)(xgc + (u0 + loff));
                __half h1 = *(const __half*)(xgc + (u1 + loff));
                __half2 n01 = *(__half2*)&nd0;
                acc0 = __hfma2(n01, __halves2half2(h0, h1), acc0);
            }
        }
        float accf = (__low2float(acc0) + __high2float(acc0))
                   + (__low2float(acc1) + __high2float(acc1));
        float di = dinv[node];
        float v = accf + di * di * (float)xg[(size_t)node * 16 + lane16] + bf;
        hpg[(size_t)node * 16 + lane16] = (half_t)v;
        s += v;
        s2 += v * v;
    }
    __shared__ float ls[256], ls2[256];
    ls[threadIdx.x] = s;
    ls2[threadIdx.x] = s2;
    __syncthreads();
    if (threadIdx.x < 16) {
        float a = 0.f, aa = 0.f;
#pragma unroll
        for (int k = 0; k < 16; k++) {
            a += ls[k * 16 + threadIdx.x];
            aa += ls2[k * 16 + threadIdx.x];
        }
        atomicAdd(&stats[g * 16 + threadIdx.x], a);
        atomicAdd(&stats[64 + g * 16 + threadIdx.x], aa);
    }
}

// -------- layer 3: BN + ReLU from fp16 planes -> fp32 node_embs + segsum -----
__global__ __launch_bounds__(256) void bn_relu_seg_kernel(const half_t* __restrict__ hpl,
                                                          float* __restrict__ h3,
                                                          const float* __restrict__ stats,
                                                          const float* __restrict__ gamma,
                                                          const float* __restrict__ beta,
                                                          const int* __restrict__ batch,
                                                          float* __restrict__ gemb,
                                                          int n_nodes) {
    int g = blockIdx.x * blockDim.x + threadIdx.x;
    int f = g & 63;
    int wave = g >> 6;
    int nwaves = (gridDim.x * blockDim.x) >> 6;
    int chunk = (n_nodes + nwaves - 1) / nwaves;
    int n0 = wave * chunk;
    int n1 = n0 + chunk;
    if (n1 > n_nodes) n1 = n_nodes;
    if (n0 >= n_nodes) return;
    float mean = stats[f] * (1.0f / N_NODES);
    float var = stats[64 + f] * (1.0f / N_NODES) - mean * mean;
    float sc = gamma[f] * rsqrtf(var + EPS);
    float sh = beta[f] - mean * sc;
    const half_t* hg = hpl + (size_t)(f >> 4) * GSTRIDE + (f & 15);
    int curg = batch[n0];
    float racc = 0.f;
    for (int n = n0; n < n1; n++) {
        int bg = batch[n];
        if (bg != curg) {
            atomicAdd(&gemb[(size_t)curg * HID + f], racc);
            racc = 0.f;
            curg = bg;
        }
        float v = (float)hg[(size_t)n * 16] * sc + sh;
        v = fmaxf(v, 0.f);
        h3[(size_t)n * HID + f] = v;
        racc += v;
    }
    atomicAdd(&gemb[(size_t)curg * HID + f], racc);
}

__global__ __launch_bounds__(256) void final_kernel(const float* __restrict__ gemb,
                                                    const float* __restrict__ fcW,
                                                    const float* __restrict__ fcb,
                                                    float* __restrict__ out) {
    int g = blockIdx.x * blockDim.x + threadIdx.x;
    if (g >= N_GRAPHS * N_CLS) return;
    int gr = g >> 1, c = g & 1;
    float acc = fcb[c];
#pragma unroll
    for (int k = 0; k < HID; k++) acc += gemb[gr * HID + k] * fcW[k * N_CLS + c];
    out[g] = acc;
}

// ---------------- launch ----------------

extern "C" void kernel_launch(void* const* d_in, const int* in_sizes, int n_in,
                              void* d_out, int out_size, void* d_ws, size_t ws_size,
                              hipStream_t stream) {
    const float* x    = (const float*)d_in[0];
    const int*   ei   = (const int*)d_in[1];
    const int*   batch= (const int*)d_in[2];
    const float* ew   = (const float*)d_in[3];
    const float* W1   = (const float*)d_in[4];
    const float* b1   = (const float*)d_in[5];
    const float* W2   = (const float*)d_in[6];
    const float* b2   = (const float*)d_in[7];
    const float* W3   = (const float*)d_in[8];
    const float* b3   = (const float*)d_in[9];
    const float* g1   = (const float*)d_in[10];
    const float* bt1  = (const float*)d_in[11];
    const float* g2   = (const float*)d_in[12];
    const float* bt2  = (const float*)d_in[13];
    const float* g3   = (const float*)d_in[14];
    const float* bt3  = (const float*)d_in[15];
    const float* fcW  = (const float*)d_in[16];
    const float* fcb  = (const float*)d_in[17];

    const int* row = ei;
    const int* col = ei + N_EDGES;

    // d_out layout: out [2048*2] | node_embs [100000*64] | graph_emb [2048*64]
    float* out_head  = (float*)d_out;
    float* node_embs = out_head + N_GRAPHS * N_CLS;
    float* gemb      = node_embs + (size_t)N_NODES * HID;

    // ws layout with lifetime overlays:
    //  R0 (12.8 MB): xwh planes
    //  R1 (12.8 MB): EA (CSR build) -> h fp16 planes (written after EA dead)
    //  R2 (10.2 MB): srcoff u32[EMAX2] + normh f16[EMAX2]
    char* bse = (char*)d_ws;
    half_t* xwh = (half_t*)bse;                        // R0
    char* r1 = bse + (size_t)N_NODES * HID * 2;        // 12.8e6 (16-aligned)
    int2*   EA  = (int2*)r1;                           // R1
    half_t* hpl = (half_t*)r1;                         // h fp16 planes
    char* r2 = r1 + (size_t)N_NODES * HID * 2;
    unsigned int* srcoff = (unsigned int*)r2;          // EMAX2 u32
    half_t* normh = (half_t*)(srcoff + EMAX2);         // EMAX2 f16
    char* r3 = r2 + (size_t)EMAX2 * 6;
    float* dinv  = (float*)r3;                         // 400 KB
    float* stats3 = dinv + N_NODES;                    // 3 x 128 floats
    int*   ptr   = (int*)(stats3 + 384);               // (N+1) ints
    int*   histG = ptr + N_NODES + 1;                  // NBUCK*ABLOCKS
    int*   bsumA = histG + NBUCK * ABLOCKS;            // NBUCK
    int*   histD = bsumA + NBUCK + 4;                  // 256*NBLK2
    int*   rowTot = histD + 256 * NBLK2;               // 256
    int*   nodeExcl = rowTot + 256;                    // 256
    int*   edgeExcl = nodeExcl + 256;                  // 256
    int*   perm   = edgeExcl + 256;                    // N
    int*   newbase= perm + N_NODES;                    // N
    int*   ptrS   = newbase + N_NODES;                 // N+1

    const int B   = 256;
    const int gGS = 1024;   // grid-stride
    const int gGA = 2048;   // gather (mult of 8)

    // ---- upfront zeroing (pads, stats, gemb) ----
    hipMemsetAsync(srcoff, 0, (size_t)EMAX2 * 6, stream);
    hipMemsetAsync(stats3, 0, 384 * sizeof(float), stream);
    hipMemsetAsync(gemb, 0, (size_t)N_GRAPHS * HID * sizeof(float), stream);

    // ---- CSR build: LDS counting sort, zero global atomics ----
    histA_kernel<<<ABLOCKS, B, 0, stream>>>(col, histG);
    scanS1_kernel<<<NBUCK, B, 0, stream>>>(histG, bsumA);
    topscan_kernel<<<1, 512, 0, stream>>>(bsumA, NBUCK);
    scanS3_kernel<<<NBUCK, B, 0, stream>>>(histG, bsumA, ptr);
    scatterA_kernel<<<ABLOCKS, B, 0, stream>>>(row, col, ew, histG, EA);
    bucketA_kernel<<<NBUCK, B, 0, stream>>>(EA, bsumA, ptr, dinv);

    // ---- degree sort of nodes (even-padded edge layout) ----
    histD_kernel<<<NBLK2, B, 0, stream>>>(ptr, histD);
    scanD1_kernel<<<256, 128, 0, stream>>>(histD, rowTot);
    topscanD_kernel<<<1, 256, 0, stream>>>(rowTot, nodeExcl, edgeExcl, ptrS);
    scanD3_kernel<<<256, 128, 0, stream>>>(histD, nodeExcl);
    scatterD_kernel<<<NBLK2, B, 0, stream>>>(ptr, histD, nodeExcl, edgeExcl,
                                             perm, ptrS, newbase);
    bucketB_kernel<<<NBUCK, B, 0, stream>>>(EA, bsumA, newbase, dinv, srcoff, normh);

    float* h3 = node_embs;  // fp32 post-BN output (written by bn_relu_seg)

    // ---- layer 1 ----
    gemm_kernel<IN_F><<<gGS, B, 0, stream>>>(x, W1, xwh, N_NODES);
    gather_stats_kernel<<<gGA, B, 0, stream>>>(ptrS, perm, srcoff,
                                               (const unsigned int*)normh, xwh,
                                               dinv, b1, hpl, stats3, N_NODES);

    // ---- layer 2 (BN1+ReLU fused into MFMA GEMM; fp16 h planes in) ----
    gemm_bn_mfma_kernel<<<gGS, B, 0, stream>>>(hpl, W2, stats3, g1, bt1, xwh, N_NODES);
    gather_stats_kernel<<<gGA, B, 0, stream>>>(ptrS, perm, srcoff,
                                               (const unsigned int*)normh, xwh,
                                               dinv, b2, hpl, stats3 + 128, N_NODES);

    // ---- layer 3 (BN2+ReLU fused into MFMA GEMM) ----
    gemm_bn_mfma_kernel<<<gGS, B, 0, stream>>>(hpl, W3, stats3 + 128, g2, bt2, xwh, N_NODES);
    gather_stats_kernel<<<gGA, B, 0, stream>>>(ptrS, perm, srcoff,
                                               (const unsigned int*)normh, xwh,
                                               dinv, b3, hpl, stats3 + 256, N_NODES);

    // ---- BN3 + ReLU (from fp16 planes) + node_embs + segment-sum ----
    bn_relu_seg_kernel<<<gGS, B, 0, stream>>>(hpl, h3, stats3 + 256, g3, bt3,
                                              batch, gemb, N_NODES);

    // ---- readout ----
    final_kernel<<<(N_GRAPHS * N_CLS + B - 1) / B, B, 0, stream>>>(gemb, fcW, fcb, out_head);
}